// Round 2
// baseline (106.265 us; speedup 1.0000x reference)
//
#include <hip/hip_runtime.h>

typedef short s16x8 __attribute__((ext_vector_type(8)));
typedef float f32x4 __attribute__((ext_vector_type(4)));

constexpr int F  = 24;
constexpr int NP = 276;   // F*(F-1)/2
constexpr int E  = 64;

__device__ __forceinline__ unsigned short f2bf(float f) {
    unsigned int u = __builtin_bit_cast(unsigned int, f);
    return (unsigned short)((u + 0x7FFFu + ((u >> 16) & 1u)) >> 16);  // RNE
}

__device__ __forceinline__ s16x8 cvt8(float4 lo, float4 hi) {
    s16x8 a;
    a[0] = (short)f2bf(lo.x); a[1] = (short)f2bf(lo.y);
    a[2] = (short)f2bf(lo.z); a[3] = (short)f2bf(lo.w);
    a[4] = (short)f2bf(hi.x); a[5] = (short)f2bf(hi.y);
    a[6] = (short)f2bf(hi.z); a[7] = (short)f2bf(hi.w);
    return a;
}

__global__ __launch_bounds__(256)
void bilinear_kernel(const float* __restrict__ x, const float* __restrict__ W,
                     float* __restrict__ out)
{
    __shared__ unsigned int BtU[2048];   // 8 KB: W[p]^T in bf16, XOR-swizzled

    const int p    = blockIdx.x;
    const int b0   = blockIdx.y * 256;
    const int tid  = threadIdx.x;
    const int wv   = tid >> 6;
    const int ln   = tid & 63;
    const int lrow = ln & 15;        // fragment row/col within 16
    const int lq   = ln >> 4;        // quarter-wave index

    // decode pair (i, j)
    int i = 0, rem = p;
    while (rem >= F - 1 - i) { rem -= F - 1 - i; ++i; }
    const int j = i + 1 + rem;

    float4 rA[2][4];   // raw x_i (double-buffered)
    f32x4  rJ[2][4];   // raw x_j float4s

#define ISSUE(S, B) do {                                                    \
    int b_ = b0 + (S) * 64 + wv * 16 + lrow;                                \
    const float* xi_ = x + ((size_t)b_ * F + i) * E;                        \
    const float* xj_ = x + ((size_t)b_ * F + j) * E;                        \
    rA[B][0] = *reinterpret_cast<const float4*>(xi_ + lq * 8);              \
    rA[B][1] = *reinterpret_cast<const float4*>(xi_ + lq * 8 + 4);          \
    rA[B][2] = *reinterpret_cast<const float4*>(xi_ + 32 + lq * 8);         \
    rA[B][3] = *reinterpret_cast<const float4*>(xi_ + 32 + lq * 8 + 4);     \
    rJ[B][0] = *reinterpret_cast<const f32x4*>(xj_ + lq * 4);               \
    rJ[B][1] = *reinterpret_cast<const f32x4*>(xj_ + 16 + lq * 4);          \
    rJ[B][2] = *reinterpret_cast<const f32x4*>(xj_ + 32 + lq * 4);          \
    rJ[B][3] = *reinterpret_cast<const f32x4*>(xj_ + 48 + lq * 4);          \
} while (0)

    // pass-0 loads issued before staging (independent of LDS)
    ISSUE(0, 0);

    // ---- stage W[p]^T into LDS as bf16, byte-XOR swizzled (same as R1) ----
    const float* Wp = W + (size_t)p * E * E;
    #pragma unroll
    for (int it = 0; it < 8; ++it) {
        int q  = tid + it * 256;
        int f  = q & 63;
        int e2 = q >> 6;
        float w0 = Wp[(2 * e2) * E + f];
        float w1 = Wp[(2 * e2 + 1) * E + f];
        unsigned int pk = (unsigned int)f2bf(w0) | ((unsigned int)f2bf(w1) << 16);
        BtU[f * 32 + (e2 ^ ((f & 7) << 2))] = pk;
    }
    __syncthreads();

    const unsigned short* Bts = reinterpret_cast<const unsigned short*>(BtU);

    // W^T fragments — now the MFMA *A* operand: row = f (lrow + 16m), k = e
    s16x8 wfrag[4][2];
    #pragma unroll
    for (int m = 0; m < 4; ++m) {
        int fc = m * 16 + lrow;
        #pragma unroll
        for (int kk = 0; kk < 2; ++kk) {
            int k0 = kk * 32 + lq * 8;
            int sidx = fc * 64 + (k0 ^ ((fc & 7) << 3));
            wfrag[m][kk] = *reinterpret_cast<const s16x8*>(&Bts[sidx]);
        }
    }

    #pragma unroll
    for (int s = 0; s < 4; ++s) {
        const int cur = s & 1;
        if (s < 3) ISSUE(s + 1, cur ^ 1);   // prefetch next batch sub-tile

        // x_i fragment — MFMA *B* operand: col = b (lrow), k = e
        s16x8 xf0 = cvt8(rA[cur][0], rA[cur][1]);
        s16x8 xf1 = cvt8(rA[cur][2], rA[cur][3]);

        // D[f][b]: row = f = m*16 + lq*4 + r, col = b = lrow
        f32x4 acc[4];
        #pragma unroll
        for (int m = 0; m < 4; ++m) {
            acc[m] = (f32x4){0.f, 0.f, 0.f, 0.f};
            acc[m] = __builtin_amdgcn_mfma_f32_16x16x32_bf16(wfrag[m][0], xf0, acc[m], 0, 0, 0);
            acc[m] = __builtin_amdgcn_mfma_f32_16x16x32_bf16(wfrag[m][1], xf1, acc[m], 0, 0, 0);
        }

        // epilogue: thread owns f = m*16 + lq*4 .. +3 for batch b → float4 stores
        const int b = b0 + s * 64 + wv * 16 + lrow;
        float* op = out + ((size_t)b * NP + p) * E + lq * 4;
        #pragma unroll
        for (int m = 0; m < 4; ++m) {
            f32x4 o = acc[m] * rJ[cur][m];
            __builtin_nontemporal_store(o, reinterpret_cast<f32x4*>(op + m * 16));
        }
    }
#undef ISSUE
}

extern "C" void kernel_launch(void* const* d_in, const int* in_sizes, int n_in,
                              void* d_out, int out_size, void* d_ws, size_t ws_size,
                              hipStream_t stream)
{
    const float* x = (const float*)d_in[0];
    const float* W = (const float*)d_in[1];
    float* out = (float*)d_out;
    dim3 grid(NP, 4096 / 256, 1);
    bilinear_kernel<<<grid, 256, 0, stream>>>(x, W, out);
}

// Round 3
// 105.961 us; speedup vs baseline: 1.0029x; 1.0029x over previous
//
#include <hip/hip_runtime.h>

typedef short s16x8 __attribute__((ext_vector_type(8)));
typedef float f32x4 __attribute__((ext_vector_type(4)));

constexpr int F  = 24;
constexpr int NP = 276;   // F*(F-1)/2
constexpr int E  = 64;

__device__ __forceinline__ unsigned short f2bf(float f) {
    unsigned int u = __builtin_bit_cast(unsigned int, f);
    return (unsigned short)((u + 0x7FFFu + ((u >> 16) & 1u)) >> 16);  // RNE
}

__device__ __forceinline__ s16x8 cvt8(float4 lo, float4 hi) {
    s16x8 a;
    a[0] = (short)f2bf(lo.x); a[1] = (short)f2bf(lo.y);
    a[2] = (short)f2bf(lo.z); a[3] = (short)f2bf(lo.w);
    a[4] = (short)f2bf(hi.x); a[5] = (short)f2bf(hi.y);
    a[6] = (short)f2bf(hi.z); a[7] = (short)f2bf(hi.w);
    return a;
}

__global__ __launch_bounds__(256)
void bilinear_kernel(const float* __restrict__ x, const float* __restrict__ W,
                     float* __restrict__ out)
{
    __shared__ unsigned int BtU[2048];   // 8 KB: W[p]^T in bf16, XOR-swizzled

    const int p    = blockIdx.x;
    const int b0   = blockIdx.y * 256;
    const int tid  = threadIdx.x;
    const int wv   = tid >> 6;
    const int ln   = tid & 63;
    const int lrow = ln & 15;        // fragment row/col within 16
    const int lq   = ln >> 4;        // quarter-wave index

    // decode pair (i, j)
    int i = 0, rem = p;
    while (rem >= F - 1 - i) { rem -= F - 1 - i; ++i; }
    const int j = i + 1 + rem;

    // ---- stage W[p]^T into LDS as bf16, byte-XOR swizzled ----
    const float* Wp = W + (size_t)p * E * E;
    #pragma unroll
    for (int it = 0; it < 8; ++it) {
        int q  = tid + it * 256;
        int f  = q & 63;
        int e2 = q >> 6;
        float w0 = Wp[(2 * e2) * E + f];
        float w1 = Wp[(2 * e2 + 1) * E + f];
        unsigned int pk = (unsigned int)f2bf(w0) | ((unsigned int)f2bf(w1) << 16);
        BtU[f * 32 + (e2 ^ ((f & 7) << 2))] = pk;
    }
    __syncthreads();

    const unsigned short* Bts = reinterpret_cast<const unsigned short*>(BtU);

    #pragma unroll 1
    for (int s = 0; s < 4; ++s) {
        const int b = b0 + s * 64 + wv * 16 + lrow;
        const float* xi_ = x + ((size_t)b * F + i) * E;
        const float* xj_ = x + ((size_t)b * F + j) * E;

        // x_i fragment — MFMA B operand: col = b (lrow), k = e
        float4 a0 = *reinterpret_cast<const float4*>(xi_ + lq * 8);
        float4 a1 = *reinterpret_cast<const float4*>(xi_ + lq * 8 + 4);
        float4 a2 = *reinterpret_cast<const float4*>(xi_ + 32 + lq * 8);
        float4 a3 = *reinterpret_cast<const float4*>(xi_ + 32 + lq * 8 + 4);

        // x_j in fp32 for the epilogue multiply (f-major float4s)
        f32x4 rJ0 = *reinterpret_cast<const f32x4*>(xj_ + lq * 4);
        f32x4 rJ1 = *reinterpret_cast<const f32x4*>(xj_ + 16 + lq * 4);
        f32x4 rJ2 = *reinterpret_cast<const f32x4*>(xj_ + 32 + lq * 4);
        f32x4 rJ3 = *reinterpret_cast<const f32x4*>(xj_ + 48 + lq * 4);

        s16x8 xf0 = cvt8(a0, a1);
        s16x8 xf1 = cvt8(a2, a3);

        float* op = out + ((size_t)b * NP + p) * E + lq * 4;

        // m-loop: read W fragment from LDS, 2 MFMAs, multiply, store.
        // D[row=f][col=b]: thread (lq,lrow) owns f = m*16 + lq*4 .. +3, b = lrow col.
        #pragma unroll
        for (int m = 0; m < 4; ++m) {
            int fc = m * 16 + lrow;
            int sidx0 = fc * 64 + ((lq * 8) ^ ((fc & 7) << 3));
            int sidx1 = fc * 64 + ((32 + lq * 8) ^ ((fc & 7) << 3));
            s16x8 w0 = *reinterpret_cast<const s16x8*>(&Bts[sidx0]);
            s16x8 w1 = *reinterpret_cast<const s16x8*>(&Bts[sidx1]);

            f32x4 acc = (f32x4){0.f, 0.f, 0.f, 0.f};
            acc = __builtin_amdgcn_mfma_f32_16x16x32_bf16(w0, xf0, acc, 0, 0, 0);
            acc = __builtin_amdgcn_mfma_f32_16x16x32_bf16(w1, xf1, acc, 0, 0, 0);

            f32x4 rj = (m == 0) ? rJ0 : (m == 1) ? rJ1 : (m == 2) ? rJ2 : rJ3;
            f32x4 o = acc * rj;
            *reinterpret_cast<f32x4*>(op + m * 16) = o;
        }
    }
}

extern "C" void kernel_launch(void* const* d_in, const int* in_sizes, int n_in,
                              void* d_out, int out_size, void* d_ws, size_t ws_size,
                              hipStream_t stream)
{
    const float* x = (const float*)d_in[0];
    const float* W = (const float*)d_in[1];
    float* out = (float*)d_out;
    dim3 grid(NP, 4096 / 256, 1);
    bilinear_kernel<<<grid, 256, 0, stream>>>(x, W, out);
}

// Round 4
// 83.159 us; speedup vs baseline: 1.2779x; 1.2742x over previous
//
#include <hip/hip_runtime.h>

typedef short s16x8 __attribute__((ext_vector_type(8)));
typedef float f32x4 __attribute__((ext_vector_type(4)));

constexpr int F  = 24;
constexpr int NP = 276;   // F*(F-1)/2
constexpr int E  = 64;

__device__ __forceinline__ unsigned short f2bf(float f) {
    unsigned int u = __builtin_bit_cast(unsigned int, f);
    return (unsigned short)((u + 0x7FFFu + ((u >> 16) & 1u)) >> 16);  // RNE
}

__global__ __launch_bounds__(256)
void bilinear_kernel(const float* __restrict__ x, const float* __restrict__ W,
                     float* __restrict__ out)
{
    __shared__ unsigned int BtU[2048];   // 8 KB: W[p]^T in bf16, XOR-swizzled

    // ---- XCD-aware swizzle (T1): all 276 p-blocks of one batch window on
    // one XCD, so their shared 1.5 MB x-slice stays L2-resident.
    // bid -> (xcd = bid%8, idx = bid/8); window = xcd*2 + idx/276; p = idx%276.
    const int bid = blockIdx.x;
    const int xcd = bid & 7;
    const int idx = bid >> 3;              // 0..551
    const int wl  = (idx >= NP) ? 1 : 0;
    const int p   = idx - wl * NP;
    const int b0  = (xcd * 2 + wl) * 256;

    const int tid = threadIdx.x;
    const int wv  = tid >> 6;
    const int ln  = tid & 63;

    // decode pair (i, j)
    int i = 0, rem = p;
    while (rem >= F - 1 - i) { rem -= F - 1 - i; ++i; }
    const int j = i + 1 + rem;

    // ---- stage W[p]^T into LDS as bf16, byte-XOR swizzled ----
    const float* Wp = W + (size_t)p * E * E;
    #pragma unroll
    for (int it = 0; it < 8; ++it) {
        int q  = tid + it * 256;
        int f  = q & 63;
        int e2 = q >> 6;
        float w0 = Wp[(2 * e2) * E + f];
        float w1 = Wp[(2 * e2 + 1) * E + f];
        unsigned int pk = (unsigned int)f2bf(w0) | ((unsigned int)f2bf(w1) << 16);
        BtU[f * 32 + (e2 ^ ((f & 7) << 2))] = pk;
    }
    __syncthreads();

    const unsigned short* Bts = reinterpret_cast<const unsigned short*>(BtU);

    const int lrow = ln & 15;        // A row / B col / D col within 16
    const int lq   = ln >> 4;        // quarter-wave index

    // B fragments: 4 n-blocks x 2 k-halves, loaded once, reused for all subtiles
    s16x8 bfrag[4][2];
    #pragma unroll
    for (int n = 0; n < 4; ++n) {
        int fc = n * 16 + lrow;
        #pragma unroll
        for (int kk = 0; kk < 2; ++kk) {
            int k0 = kk * 32 + lq * 8;
            int sidx = fc * 64 + (k0 ^ ((fc & 7) << 3));
            bfrag[n][kk] = *reinterpret_cast<const s16x8*>(&Bts[sidx]);
        }
    }

    #pragma unroll 1
    for (int s = 0; s < 4; ++s) {
        const int mbase = s * 64 + wv * 16;

        // A fragments straight from global (L2-hot after swizzle)
        s16x8 afrag[2];
        #pragma unroll
        for (int kk = 0; kk < 2; ++kk) {
            int b  = b0 + mbase + lrow;
            int k0 = kk * 32 + lq * 8;
            const float4* ap = reinterpret_cast<const float4*>(
                x + ((size_t)b * F + i) * E + k0);
            float4 lo = ap[0], hi = ap[1];
            s16x8 a;
            a[0] = (short)f2bf(lo.x); a[1] = (short)f2bf(lo.y);
            a[2] = (short)f2bf(lo.z); a[3] = (short)f2bf(lo.w);
            a[4] = (short)f2bf(hi.x); a[5] = (short)f2bf(hi.y);
            a[6] = (short)f2bf(hi.z); a[7] = (short)f2bf(hi.w);
            afrag[kk] = a;
        }

        f32x4 acc[4];
        #pragma unroll
        for (int n = 0; n < 4; ++n) {
            acc[n] = (f32x4){0.f, 0.f, 0.f, 0.f};
            acc[n] = __builtin_amdgcn_mfma_f32_16x16x32_bf16(afrag[0], bfrag[n][0], acc[n], 0, 0, 0);
            acc[n] = __builtin_amdgcn_mfma_f32_16x16x32_bf16(afrag[1], bfrag[n][1], acc[n], 0, 0, 0);
        }

        // epilogue: D[row=(lq*4+r)][col=lrow]; multiply by xj in fp32, store
        #pragma unroll
        for (int n = 0; n < 4; ++n) {
            int fc = n * 16 + lrow;
            #pragma unroll
            for (int r = 0; r < 4; ++r) {
                int m = mbase + lq * 4 + r;
                int b = b0 + m;
                float xj = x[((size_t)b * F + j) * E + fc];
                out[((size_t)b * NP + p) * E + fc] = acc[n][r] * xj;
            }
        }
    }
}

extern "C" void kernel_launch(void* const* d_in, const int* in_sizes, int n_in,
                              void* d_out, int out_size, void* d_ws, size_t ws_size,
                              hipStream_t stream)
{
    const float* x = (const float*)d_in[0];
    const float* W = (const float*)d_in[1];
    float* out = (float*)d_out;
    dim3 grid(NP * 16, 1, 1);   // 4416 = 8 XCDs x 552
    bilinear_kernel<<<grid, 256, 0, stream>>>(x, W, out);
}